// Round 3
// baseline (3768.301 us; speedup 1.0000x reference)
//
#include <hip/hip_runtime.h>

#define BATCH 2048
#define SEQT  2000
#define H1    51

__device__ __forceinline__ float rl(float v, int lane) {
    return __int_as_float(__builtin_amdgcn_readlane(__float_as_int(v), lane));
}
__device__ __forceinline__ float sigf(float x) {
    return 1.f / (1.f + __expf(-x));
}
__device__ __forceinline__ float tanhfast(float x) {
    return 1.f - 2.f / (__expf(2.f * x) + 1.f);
}

// apply M to 0..50
#define R51(M) M(0) M(1) M(2) M(3) M(4) M(5) M(6) M(7) M(8) M(9) \
    M(10) M(11) M(12) M(13) M(14) M(15) M(16) M(17) M(18) M(19) \
    M(20) M(21) M(22) M(23) M(24) M(25) M(26) M(27) M(28) M(29) \
    M(30) M(31) M(32) M(33) M(34) M(35) M(36) M(37) M(38) M(39) \
    M(40) M(41) M(42) M(43) M(44) M(45) M(46) M(47) M(48) M(49) M(50)

__global__ void __launch_bounds__(64)
__attribute__((amdgpu_waves_per_eu(2, 2)))
lstm_seq_kernel(const float* __restrict__ input,
                const float* __restrict__ W_ih1,
                const float* __restrict__ W_hh1,
                const float* __restrict__ b_ih1,
                const float* __restrict__ b_hh1,
                const float* __restrict__ W_ih3,
                const float* __restrict__ W_hh3,
                const float* __restrict__ b_ih3,
                const float* __restrict__ b_hh3,
                float* __restrict__ out) {
    const int b = blockIdx.x;      // one batch row per wave
    const int j = threadIdx.x;     // lane j owns hidden unit j (j<51)
    const bool act = (j < H1);
    const int js = act ? j : 0;    // lanes >=51 mirror unit 0 (finite, unused)

    const float* r_i = W_hh1 + (size_t)(0 * H1 + js) * H1;
    const float* r_f = W_hh1 + (size_t)(1 * H1 + js) * H1;
    const float* r_g = W_hh1 + (size_t)(2 * H1 + js) * H1;
    const float* r_o = W_hh1 + (size_t)(3 * H1 + js) * H1;

    // ---- 204 individually-named weight registers (no arrays -> no SROA failure)
#define DECLW(k) float wi##k, wf##k, wg##k, wo##k;
    R51(DECLW)
#undef DECLW
#define LOADW(k) wi##k = r_i[k]; wf##k = r_f[k]; wg##k = r_g[k]; wo##k = r_o[k];
    R51(LOADW)
#undef LOADW

    const float wihx_i = W_ih1[js];
    const float wihx_f = W_ih1[H1 + js];
    const float wihx_g = W_ih1[2 * H1 + js];
    const float wihx_o = W_ih1[3 * H1 + js];
    const float bias_i = b_ih1[js] + b_hh1[js];
    const float bias_f = b_ih1[H1 + js] + b_hh1[H1 + js];
    const float bias_g = b_ih1[2 * H1 + js] + b_hh1[2 * H1 + js];
    const float bias_o = b_ih1[3 * H1 + js] + b_hh1[3 * H1 + js];

    // lstm3 input weights: inactive lanes contribute 0 to the reduction
    float wih3_0 = act ? W_ih3[0 * H1 + j] : 0.f;
    float wih3_1 = act ? W_ih3[1 * H1 + j] : 0.f;
    float wih3_2 = act ? W_ih3[2 * H1 + j] : 0.f;
    float wih3_3 = act ? W_ih3[3 * H1 + j] : 0.f;
    const float whh3_0 = W_hh3[0], whh3_1 = W_hh3[1];
    const float whh3_2 = W_hh3[2], whh3_3 = W_hh3[3];
    const float b3_0 = b_ih3[0] + b_hh3[0];
    const float b3_1 = b_ih3[1] + b_hh3[1];
    const float b3_2 = b_ih3[2] + b_hh3[2];
    const float b3_3 = b_ih3[3] + b_hh3[3];

    float h1v = 0.f, c1v = 0.f;   // unit j state (distributed across lanes)
    float h3 = 0.f, c3 = 0.f;     // uniform scalar state

    const size_t rowbase = (size_t)b * SEQT;

#pragma unroll 1
    for (int t0 = 0; t0 < SEQT; t0 += 64) {
        const int idx = t0 + j;
        float xv = (idx < SEQT) ? input[rowbase + idx] : 0.f;
        const int tend = (SEQT - t0 < 64) ? (SEQT - t0) : 64;
        float outv = 0.f;

#pragma unroll 1
        for (int tt = 0; tt < tend; ++tt) {
            const float xt = rl(xv, tt);

            // ---- LSTM1 gates ----
            float ai = fmaf(xt, wihx_i, bias_i);
            float af = fmaf(xt, wihx_f, bias_f);
            float ag = fmaf(xt, wihx_g, bias_g);
            float ao = fmaf(xt, wihx_o, bias_o);
#define MACK(k) { const float hk = rl(h1v, k); \
            ai = fmaf(hk, wi##k, ai); af = fmaf(hk, wf##k, af); \
            ag = fmaf(hk, wg##k, ag); ao = fmaf(hk, wo##k, ao); }
            R51(MACK)
#undef MACK
            c1v = sigf(af) * c1v + sigf(ai) * tanhfast(ag);
            h1v = sigf(ao) * tanhfast(c1v);

            // ---- LSTM3 (H3 = 1): reduce c1 @ W_ih3 across lanes ----
            float p0 = c1v * wih3_0;
            float p1 = c1v * wih3_1;
            float p2 = c1v * wih3_2;
            float p3 = c1v * wih3_3;
#pragma unroll
            for (int m = 1; m < 64; m <<= 1) {
                p0 += __shfl_xor(p0, m);
                p1 += __shfl_xor(p1, m);
                p2 += __shfl_xor(p2, m);
                p3 += __shfl_xor(p3, m);
            }
            const float gi = fmaf(whh3_0, h3, p0) + b3_0;
            const float gf = fmaf(whh3_1, h3, p1) + b3_1;
            const float gg = fmaf(whh3_2, h3, p2) + b3_2;
            const float go = fmaf(whh3_3, h3, p3) + b3_3;
            c3 = sigf(gf) * c3 + sigf(gi) * tanhfast(gg);
            h3 = sigf(go) * tanhfast(c3);

            // lane tt captures this step's uniform c3 (coalesced store later)
            outv = (j == tt) ? c3 : outv;
        }

        if (idx < SEQT) out[rowbase + idx] = outv;
    }
}

extern "C" void kernel_launch(void* const* d_in, const int* in_sizes, int n_in,
                              void* d_out, int out_size, void* d_ws, size_t ws_size,
                              hipStream_t stream) {
    const float* input = (const float*)d_in[0];
    const float* W_ih1 = (const float*)d_in[1];
    const float* W_hh1 = (const float*)d_in[2];
    const float* b_ih1 = (const float*)d_in[3];
    const float* b_hh1 = (const float*)d_in[4];
    const float* W_ih3 = (const float*)d_in[5];
    const float* W_hh3 = (const float*)d_in[6];
    const float* b_ih3 = (const float*)d_in[7];
    const float* b_hh3 = (const float*)d_in[8];
    float* out = (float*)d_out;

    lstm_seq_kernel<<<BATCH, 64, 0, stream>>>(
        input, W_ih1, W_hh1, b_ih1, b_hh1, W_ih3, W_hh3, b_ih3, b_hh3, out);
}

// Round 4
// 3700.278 us; speedup vs baseline: 1.0184x; 1.0184x over previous
//
#include <hip/hip_runtime.h>

#define BATCH 2048
#define SEQT  2000
#define H1    51

__device__ __forceinline__ float rl(float v, int lane) {
    return __int_as_float(__builtin_amdgcn_readlane(__float_as_int(v), lane));
}
__device__ __forceinline__ float sigf(float x) {
    return 1.f / (1.f + __expf(-x));
}
__device__ __forceinline__ float tanhfast(float x) {
    return 1.f - 2.f / (__expf(2.f * x) + 1.f);
}

// apply M to 0..50
#define R51(M) M(0) M(1) M(2) M(3) M(4) M(5) M(6) M(7) M(8) M(9) \
    M(10) M(11) M(12) M(13) M(14) M(15) M(16) M(17) M(18) M(19) \
    M(20) M(21) M(22) M(23) M(24) M(25) M(26) M(27) M(28) M(29) \
    M(30) M(31) M(32) M(33) M(34) M(35) M(36) M(37) M(38) M(39) \
    M(40) M(41) M(42) M(43) M(44) M(45) M(46) M(47) M(48) M(49) M(50)

__global__ void __launch_bounds__(64)
__attribute__((amdgpu_waves_per_eu(2, 2)))
lstm_seq_kernel(const float* __restrict__ input,
                const float* __restrict__ W_ih1,
                const float* __restrict__ W_hh1,
                const float* __restrict__ b_ih1,
                const float* __restrict__ b_hh1,
                const float* __restrict__ W_ih3,
                const float* __restrict__ W_hh3,
                const float* __restrict__ b_ih3,
                const float* __restrict__ b_hh3,
                float* __restrict__ out) {
    const int b = blockIdx.x;      // one batch row per wave
    const int j = threadIdx.x;     // lane j owns hidden unit j (j<51)
    const bool act = (j < H1);
    const int js = act ? j : 0;    // lanes >=51 mirror unit 0 (finite, unused)

    const float* r_i = W_hh1 + (size_t)(0 * H1 + js) * H1;
    const float* r_f = W_hh1 + (size_t)(1 * H1 + js) * H1;
    const float* r_g = W_hh1 + (size_t)(2 * H1 + js) * H1;
    const float* r_o = W_hh1 + (size_t)(3 * H1 + js) * H1;

    // ---- 204 named weight registers, PINNED via opaque asm so the compiler
    // cannot rematerialize/re-load them inside the time loop.
#define DECLW(k) float wi##k, wf##k, wg##k, wo##k;
    R51(DECLW)
#undef DECLW
#define LOADW(k) wi##k = r_i[k]; wf##k = r_f[k]; wg##k = r_g[k]; wo##k = r_o[k];
    R51(LOADW)
#undef LOADW
#define PINW(k) asm volatile("" : "+v"(wi##k), "+v"(wf##k), "+v"(wg##k), "+v"(wo##k));
    R51(PINW)
#undef PINW

    const float wihx_i = W_ih1[js];
    const float wihx_f = W_ih1[H1 + js];
    const float wihx_g = W_ih1[2 * H1 + js];
    const float wihx_o = W_ih1[3 * H1 + js];
    const float bias_i = b_ih1[js] + b_hh1[js];
    const float bias_f = b_ih1[H1 + js] + b_hh1[H1 + js];
    const float bias_g = b_ih1[2 * H1 + js] + b_hh1[2 * H1 + js];
    const float bias_o = b_ih1[3 * H1 + js] + b_hh1[3 * H1 + js];

    // lstm3 input weights: inactive lanes contribute 0 to the reduction
    float wih3_0 = act ? W_ih3[0 * H1 + j] : 0.f;
    float wih3_1 = act ? W_ih3[1 * H1 + j] : 0.f;
    float wih3_2 = act ? W_ih3[2 * H1 + j] : 0.f;
    float wih3_3 = act ? W_ih3[3 * H1 + j] : 0.f;
    const float whh3_0 = W_hh3[0], whh3_1 = W_hh3[1];
    const float whh3_2 = W_hh3[2], whh3_3 = W_hh3[3];
    const float b3_0 = b_ih3[0] + b_hh3[0];
    const float b3_1 = b_ih3[1] + b_hh3[1];
    const float b3_2 = b_ih3[2] + b_hh3[2];
    const float b3_3 = b_ih3[3] + b_hh3[3];

    float h1v = 0.f, c1v = 0.f;   // unit j state (distributed across lanes)
    float h3 = 0.f, c3 = 0.f;     // uniform scalar state

    const size_t rowbase = (size_t)b * SEQT;

#pragma unroll 1
    for (int t0 = 0; t0 < SEQT; t0 += 64) {
        const int idx = t0 + j;
        float xv = (idx < SEQT) ? input[rowbase + idx] : 0.f;
        const int tend = (SEQT - t0 < 64) ? (SEQT - t0) : 64;
        float outv = 0.f;

#pragma unroll 1
        for (int tt = 0; tt < tend; ++tt) {
            const float xt = rl(xv, tt);

            // ---- LSTM1 gates ----
            float ai = fmaf(xt, wihx_i, bias_i);
            float af = fmaf(xt, wihx_f, bias_f);
            float ag = fmaf(xt, wihx_g, bias_g);
            float ao = fmaf(xt, wihx_o, bias_o);
#define MACK(k) { const float hk = rl(h1v, k); \
            ai = fmaf(hk, wi##k, ai); af = fmaf(hk, wf##k, af); \
            ag = fmaf(hk, wg##k, ag); ao = fmaf(hk, wo##k, ao); }
            R51(MACK)
#undef MACK
            c1v = sigf(af) * c1v + sigf(ai) * tanhfast(ag);
            h1v = sigf(ao) * tanhfast(c1v);

            // ---- LSTM3 (H3 = 1): reduce c1 @ W_ih3 across lanes ----
            float p0 = c1v * wih3_0;
            float p1 = c1v * wih3_1;
            float p2 = c1v * wih3_2;
            float p3 = c1v * wih3_3;
#pragma unroll
            for (int m = 1; m < 64; m <<= 1) {
                p0 += __shfl_xor(p0, m);
                p1 += __shfl_xor(p1, m);
                p2 += __shfl_xor(p2, m);
                p3 += __shfl_xor(p3, m);
            }
            const float gi = fmaf(whh3_0, h3, p0) + b3_0;
            const float gf = fmaf(whh3_1, h3, p1) + b3_1;
            const float gg = fmaf(whh3_2, h3, p2) + b3_2;
            const float go = fmaf(whh3_3, h3, p3) + b3_3;
            c3 = sigf(gf) * c3 + sigf(gi) * tanhfast(gg);
            h3 = sigf(go) * tanhfast(c3);

            // lane tt captures this step's uniform c3 (coalesced store later)
            outv = (j == tt) ? c3 : outv;
        }

        if (idx < SEQT) out[rowbase + idx] = outv;
    }
}

extern "C" void kernel_launch(void* const* d_in, const int* in_sizes, int n_in,
                              void* d_out, int out_size, void* d_ws, size_t ws_size,
                              hipStream_t stream) {
    const float* input = (const float*)d_in[0];
    const float* W_ih1 = (const float*)d_in[1];
    const float* W_hh1 = (const float*)d_in[2];
    const float* b_ih1 = (const float*)d_in[3];
    const float* b_hh1 = (const float*)d_in[4];
    const float* W_ih3 = (const float*)d_in[5];
    const float* W_hh3 = (const float*)d_in[6];
    const float* b_ih3 = (const float*)d_in[7];
    const float* b_hh3 = (const float*)d_in[8];
    float* out = (float*)d_out;

    lstm_seq_kernel<<<BATCH, 64, 0, stream>>>(
        input, W_ih1, W_hh1, b_ih1, b_hh1, W_ih3, W_hh3, b_ih3, b_hh3, out);
}

// Round 6
// 3056.925 us; speedup vs baseline: 1.2327x; 1.2105x over previous
//
#include <hip/hip_runtime.h>
#include <hip/hip_bf16.h>

#define SEQT 2000
#define NB   2048
#define H1   51
#define MROW 4            // batch rows per block
#define NBLK (NB / MROW)  // 512 blocks

typedef float f32x4 __attribute__((ext_vector_type(4)));
typedef short s16x8 __attribute__((ext_vector_type(8)));

__device__ __forceinline__ short f2bf(float f) {
    __hip_bfloat16 b(f);
    return *reinterpret_cast<short*>(&b);
}
__device__ __forceinline__ float bf2f(short s) {
    __hip_bfloat16 b;
    *reinterpret_cast<short*>(&b) = s;
    return (float)b;
}
__device__ __forceinline__ float sigf(float x) { return 1.f / (1.f + __expf(-x)); }
__device__ __forceinline__ float tanhfast(float x) { return 1.f - 2.f / (__expf(2.f * x) + 1.f); }

// K-column map (K=160, 5 tiles of 32):
//   [0,51)    A=h_hi      B=Whh_hi
//   [51,102)  A=h_lo      B=Whh_hi
//   [102,153) A=h_hi      B=Whh_lo
//   153 A=x_hi B=Wih_hi | 154 A=x_lo B=Wih_hi | 155 A=x_hi B=Wih_lo
//   156 A=1 B=b_hi | 157 A=1 B=b_lo | 158,159 A=0
// N: 204 gate rows (i,f,g,o)x51, padded to 16 tiles of 16 (B=0 beyond 204).

__global__ void __launch_bounds__(256)
__attribute__((amdgpu_waves_per_eu(2)))
lstm1_mfma_kernel(const float* __restrict__ input,
                  const float* __restrict__ W_ih1,
                  const float* __restrict__ W_hh1,
                  const float* __restrict__ b_ih1,
                  const float* __restrict__ b_hh1,
                  const float* __restrict__ W_ih3,
                  float* __restrict__ zws) {
    const int t    = threadIdx.x;
    const int w    = t >> 6;        // wave id 0..3
    const int lane = t & 63;
    const int r0   = blockIdx.x * MROW;

    __shared__ short Ast[5 * 512];      // A staging: [kt][m(16)][32] shorts
    __shared__ float G[4 * 208];        // gate preacts, rows 0..3
    __shared__ float C1s[4 * 52];       // c1 for z-phase (stride 52)
    __shared__ float Xchunk[4 * 64];    // 64 timesteps of x per row

    // ---- build B fragments (weights, hi/lo-compensated bf16) in registers ----
    // wave w owns N-tiles {w, w+4, w+8, w+12}
    s16x8 Bfr[4][5];
    {
        const int ln = lane & 15, kq = lane >> 4;
#pragma unroll
        for (int i2 = 0; i2 < 4; ++i2) {
            const int nt = w + 4 * i2;
            const int n  = nt * 16 + ln;
#pragma unroll
            for (int kt = 0; kt < 5; ++kt) {
                s16x8 bf;
#pragma unroll
                for (int j = 0; j < 8; ++j) {
                    const int k = kt * 32 + kq * 8 + j;
                    float v = 0.f;
                    if (n < 204) {
                        if (k < 51) {
                            v = bf2f(f2bf(W_hh1[n * H1 + k]));
                        } else if (k < 102) {
                            v = bf2f(f2bf(W_hh1[n * H1 + (k - 51)]));
                        } else if (k < 153) {
                            float wv = W_hh1[n * H1 + (k - 102)];
                            v = wv - bf2f(f2bf(wv));
                        } else if (k == 153 || k == 154) {
                            v = bf2f(f2bf(W_ih1[n]));
                        } else if (k == 155) {
                            float wv = W_ih1[n];
                            v = wv - bf2f(f2bf(wv));
                        } else if (k == 156) {
                            v = bf2f(f2bf(b_ih1[n] + b_hh1[n]));
                        } else if (k == 157) {
                            float bv = b_ih1[n] + b_hh1[n];
                            v = bv - bf2f(f2bf(bv));
                        }
                    }
                    bf[j] = f2bf(v);
                }
                Bfr[i2][kt] = bf;
            }
        }
    }

    // ---- z-phase weights: thread t<64 handles (m=t>>4, g=(t>>2)&3, q=t&3) ----
    float w3[13];
    if (t < 64) {
        const int g = (t >> 2) & 3, q = t & 3;
#pragma unroll
        for (int ii = 0; ii < 13; ++ii) {
            const int u = q * 13 + ii;
            w3[ii] = (u < H1) ? W_ih3[g * H1 + u] : 0.f;
        }
    }

    // ---- LDS init ----
    // zero pad rows m=4..15 of A (all 160 cols)
    for (int idx = t; idx < 12 * 160; idx += 256) {
        const int m = 4 + idx / 160, k = idx % 160;
        Ast[(k >> 5) * 512 + m * 32 + (k & 31)] = 0;
    }
    // h(-1)=0 for rows 0..3
    float c1 = 0.f;   // persistent state of this thread's (m,u) unit
    if (t < 204) {
        const int m = t & 3, u = t >> 2;
        Ast[(u >> 5) * 512 + m * 32 + (u & 31)] = 0;
        const int k2 = 51 + u, k3 = 102 + u;
        Ast[(k2 >> 5) * 512 + m * 32 + (k2 & 31)] = 0;
        Ast[(k3 >> 5) * 512 + m * 32 + (k3 & 31)] = 0;
    }
    if (t >= 204 && t < 208) {
        const int m = t - 204;
        Ast[4 * 512 + m * 32 + 28] = (short)0x3F80;  // k=156: 1.0
        Ast[4 * 512 + m * 32 + 29] = (short)0x3F80;  // k=157: 1.0
        Ast[4 * 512 + m * 32 + 30] = 0;              // k=158
        Ast[4 * 512 + m * 32 + 31] = 0;              // k=159
    }
    if (t < 4) C1s[t * 52 + 51] = 0.f;   // z-phase pad slot
    __syncthreads();

    for (int ts = 0; ts < SEQT; ++ts) {
        // ---- stage 64 timesteps of x every 64 steps ----
        if ((ts & 63) == 0) {
            const int r = t >> 6, tt = t & 63;
            const int ti = ts + tt;
            Xchunk[r * 64 + tt] =
                (ti < SEQT) ? input[(size_t)(r0 + r) * SEQT + ti] : 0.f;
            __syncthreads();
        }
        // ---- write x_t (hi/lo) into A ----
        if (t >= 204 && t < 208) {
            const int m = t - 204;
            const float x = Xchunk[m * 64 + (ts & 63)];
            const short xh = f2bf(x);
            const short xl = f2bf(x - bf2f(xh));
            Ast[4 * 512 + m * 32 + 25] = xh;   // k=153
            Ast[4 * 512 + m * 32 + 26] = xl;   // k=154
            Ast[4 * 512 + m * 32 + 27] = xh;   // k=155
        }
        __syncthreads();

        // ---- MFMA: gates = A(16x160) @ B(160x208) ----
        s16x8 Af[5];
#pragma unroll
        for (int kt = 0; kt < 5; ++kt)
            Af[kt] = *reinterpret_cast<const s16x8*>(
                &Ast[kt * 512 + (lane & 15) * 32 + (lane >> 4) * 8]);
        f32x4 acc[4];
#pragma unroll
        for (int i2 = 0; i2 < 4; ++i2) {
            acc[i2] = (f32x4){0.f, 0.f, 0.f, 0.f};
#pragma unroll
            for (int kt = 0; kt < 5; ++kt)
                acc[i2] = __builtin_amdgcn_mfma_f32_16x16x32_bf16(
                    Af[kt], Bfr[i2][kt], acc[i2], 0, 0, 0);
        }
        if (lane < 16) {   // C rows 0..3 live in lanes 0..15 (row = reg idx)
#pragma unroll
            for (int i2 = 0; i2 < 4; ++i2) {
                const int nt = w + 4 * i2;
                if (nt < 13) {
#pragma unroll
                    for (int e = 0; e < 4; ++e)
                        G[e * 208 + nt * 16 + lane] = acc[i2][e];
                }
            }
        }
        __syncthreads();

        // ---- epilogue: LSTM1 cell update for 204 (m,u) units ----
        if (t < 204) {
            const int m = t & 3, u = t >> 2;
            const float gi = G[m * 208 + u];
            const float gf = G[m * 208 + 51 + u];
            const float gg = G[m * 208 + 102 + u];
            const float go = G[m * 208 + 153 + u];
            c1 = sigf(gf) * c1 + sigf(gi) * tanhfast(gg);
            const float h1 = sigf(go) * tanhfast(c1);
            const short hh = f2bf(h1);
            const short hl = f2bf(h1 - bf2f(hh));
            Ast[(u >> 5) * 512 + m * 32 + (u & 31)] = hh;
            const int k2 = 51 + u, k3 = 102 + u;
            Ast[(k2 >> 5) * 512 + m * 32 + (k2 & 31)] = hl;
            Ast[(k3 >> 5) * 512 + m * 32 + (k3 & 31)] = hh;
            C1s[m * 52 + u] = c1;
        }
        __syncthreads();

        // ---- z-phase: z[ts][r0+m][g] = dot(W_ih3[g], c1[m]) ----
        if (t < 64) {
            const int m = t >> 4, g = (t >> 2) & 3, q = t & 3;
            float p = 0.f;
#pragma unroll
            for (int ii = 0; ii < 13; ++ii) {
                const int u = q * 13 + ii;   // u=51 slot is zeroed, w3=0
                p = fmaf(C1s[m * 52 + u], w3[ii], p);
            }
            p += __shfl_xor(p, 1);
            p += __shfl_xor(p, 2);
            if (q == 0)
                zws[(size_t)ts * (NB * 4) + (size_t)(r0 + m) * 4 + g] = p;
        }
    }
}

__global__ void __launch_bounds__(256)
lstm3_scan_kernel(const float* __restrict__ zws,
                  const float* __restrict__ W_hh3,
                  const float* __restrict__ b_ih3,
                  const float* __restrict__ b_hh3,
                  float* __restrict__ out) {
    const int row = blockIdx.x * 256 + threadIdx.x;
    const float w0 = W_hh3[0], w1 = W_hh3[1], w2 = W_hh3[2], wo3 = W_hh3[3];
    const float b0 = b_ih3[0] + b_hh3[0];
    const float b1 = b_ih3[1] + b_hh3[1];
    const float b2 = b_ih3[2] + b_hh3[2];
    const float b3v = b_ih3[3] + b_hh3[3];
    float h3 = 0.f, c3 = 0.f;
    for (int ts = 0; ts < SEQT; ++ts) {
        const float4 zz = ((const float4*)zws)[(size_t)ts * NB + row];
        const float gi = zz.x + fmaf(w0, h3, b0);
        const float gf = zz.y + fmaf(w1, h3, b1);
        const float gg = zz.z + fmaf(w2, h3, b2);
        const float go = zz.w + fmaf(wo3, h3, b3v);
        c3 = sigf(gf) * c3 + sigf(gi) * tanhfast(gg);
        h3 = sigf(go) * tanhfast(c3);
        out[(size_t)row * SEQT + ts] = c3;
    }
}

extern "C" void kernel_launch(void* const* d_in, const int* in_sizes, int n_in,
                              void* d_out, int out_size, void* d_ws, size_t ws_size,
                              hipStream_t stream) {
    const float* input = (const float*)d_in[0];
    const float* W_ih1 = (const float*)d_in[1];
    const float* W_hh1 = (const float*)d_in[2];
    const float* b_ih1 = (const float*)d_in[3];
    const float* b_hh1 = (const float*)d_in[4];
    const float* W_ih3 = (const float*)d_in[5];
    const float* W_hh3 = (const float*)d_in[6];
    const float* b_ih3 = (const float*)d_in[7];
    const float* b_hh3 = (const float*)d_in[8];
    float* out = (float*)d_out;
    float* zws = (float*)d_ws;   // [T][2048][4] fp32 = 65.5 MB

    lstm1_mfma_kernel<<<NBLK, 256, 0, stream>>>(
        input, W_ih1, W_hh1, b_ih1, b_hh1, W_ih3, zws);
    lstm3_scan_kernel<<<NB / 256, 256, 0, stream>>>(
        zws, W_hh3, b_ih3, b_hh3, out);
}

// Round 7
// 2544.814 us; speedup vs baseline: 1.4808x; 1.2012x over previous
//
#include <hip/hip_runtime.h>
#include <hip/hip_bf16.h>

#define SEQT 2000
#define NB   2048
#define H1   51
#define MROW 4            // batch rows per block
#define NBLK (NB / MROW)  // 512 blocks
#define PADR 40           // shorts per A row (80 B, 16B-aligned, bank-spread)
#define TSTR (16 * PADR)  // shorts per K-tile (16 rows)

typedef float f32x4 __attribute__((ext_vector_type(4)));
typedef short s16x8 __attribute__((ext_vector_type(8)));

__device__ __forceinline__ short f2bf(float f) { __hip_bfloat16 b(f); return *(short*)&b; }
__device__ __forceinline__ float bf2f(short s) { __hip_bfloat16 b; *(short*)&b = s; return (float)b; }
__device__ __forceinline__ float rbf(float f) { return bf2f(f2bf(f)); }
__device__ __forceinline__ float sigf(float x) { return 1.f / (1.f + __expf(-x)); }
__device__ __forceinline__ float tanhfast(float x) { return 1.f - 2.f / (__expf(2.f * x) + 1.f); }

// K-map (K=160, 5 tiles of 32):
//   col 2u   (u<51): A=h_hi(u), B=Whh_hi[n][u]
//   col 2u+1 (u<51): A=h_lo(u), B=Whh_hi[n][u]
//   col 102+u (u<51): A=h_hi(u), B=Whh_lo[n][u]
//   col 153: A=x_hi B=Wih_hi | 154: A=x_lo B=Wih_hi | 155: A=x_hi B=Wih_lo
//   col 156: A=1 B=b_hi | 157: A=1 B=b_lo | 158,159: 0
// N: n = g*51+u (204 gate rows), padded to 13 used tiles of 16.

__global__ void __launch_bounds__(256)
__attribute__((amdgpu_waves_per_eu(2)))
lstm_fused_kernel(const float* __restrict__ input,
                  const float* __restrict__ W_ih1,
                  const float* __restrict__ W_hh1,
                  const float* __restrict__ b_ih1,
                  const float* __restrict__ b_hh1,
                  const float* __restrict__ W_ih3,
                  const float* __restrict__ W_hh3,
                  const float* __restrict__ b_ih3,
                  const float* __restrict__ b_hh3,
                  float* __restrict__ out) {
    const int t = threadIdx.x;
    const int w = t >> 6;        // wave 0..3
    const int lane = t & 63;
    const int r0 = blockIdx.x * MROW;

    __shared__ short Ast[5 * TSTR];              // A staging (bank-padded)
    __shared__ __align__(16) float G[208 * 4];   // gate preacts [n][m]
    __shared__ float C1s[4 * 52];                // c1 for z-phase
    __shared__ float Obuf[4 * 64];               // c3 output chunk

    // ---- B fragments (hi/lo-compensated bf16) in registers ----
    s16x8 Bfr[4][5];
    {
        const int ln = lane & 15, kq = lane >> 4;
#pragma unroll
        for (int i2 = 0; i2 < 4; ++i2) {
            const int n = (w + 4 * i2) * 16 + ln;
#pragma unroll
            for (int kt = 0; kt < 5; ++kt) {
                s16x8 bf;
#pragma unroll
                for (int j = 0; j < 8; ++j) {
                    const int k = kt * 32 + kq * 8 + j;
                    float v = 0.f;
                    if (n < 204) {
                        if (k < 102) {
                            v = rbf(W_hh1[n * H1 + (k >> 1)]);
                        } else if (k < 153) {
                            const float wv = W_hh1[n * H1 + (k - 102)];
                            v = wv - rbf(wv);
                        } else if (k == 153 || k == 154) {
                            v = rbf(W_ih1[n]);
                        } else if (k == 155) {
                            const float wv = W_ih1[n];
                            v = wv - rbf(wv);
                        } else if (k == 156) {
                            v = rbf(b_ih1[n] + b_hh1[n]);
                        } else if (k == 157) {
                            const float bv = b_ih1[n] + b_hh1[n];
                            v = bv - rbf(bv);
                        }
                    }
                    bf[j] = f2bf(v);
                }
                Bfr[i2][kt] = bf;
            }
        }
    }

    // ---- z-phase weights: thread t<64: (m=t>>4, g=(t>>2)&3, q=t&3) ----
    float w3[13];
#pragma unroll
    for (int ii = 0; ii < 13; ++ii) w3[ii] = 0.f;
    if (t < 64) {
        const int g = (t >> 2) & 3, q = t & 3;
#pragma unroll
        for (int ii = 0; ii < 13; ++ii) {
            const int u = q * 13 + ii;
            w3[ii] = (u < H1) ? W_ih3[g * H1 + u] : 0.f;
        }
    }
    const float whh3_0 = W_hh3[0], whh3_1 = W_hh3[1];
    const float whh3_2 = W_hh3[2], whh3_3 = W_hh3[3];
    const float b3_0 = b_ih3[0] + b_hh3[0];
    const float b3_1 = b_ih3[1] + b_hh3[1];
    const float b3_2 = b_ih3[2] + b_hh3[2];
    const float b3_3 = b_ih3[3] + b_hh3[3];

    // ---- LDS init ----
    for (int idx = t; idx < 5 * TSTR; idx += 256) Ast[idx] = 0;
    if (t < 4) {
        const int m = t;
        Ast[4 * TSTR + m * PADR + 28] = (short)0x3F80;  // col 156: A=1.0
        Ast[4 * TSTR + m * PADR + 29] = (short)0x3F80;  // col 157: A=1.0
        const float x0 = input[(size_t)(r0 + m) * SEQT];
        const short xh = f2bf(x0), xl = f2bf(x0 - bf2f(xh));
        Ast[4 * TSTR + m * PADR + 25] = xh;  // col 153
        Ast[4 * TSTR + m * PADR + 26] = xl;  // col 154
        Ast[4 * TSTR + m * PADR + 27] = xh;  // col 155
        C1s[m * 52 + 51] = 0.f;
    }
    float xreg = 0.f;
    if (t >= 204 && t < 208)
        xreg = input[(size_t)(r0 + t - 204) * SEQT + 1];
    float c1 = 0.f;            // LSTM1 state of this thread's (m,u)
    float h3 = 0.f, c3 = 0.f;  // LSTM3 state (wave 0, per 16-lane group)
    __syncthreads();

    for (int ts = 0; ts < SEQT; ++ts) {
        // ---- A-frags (only the 4 real rows touch LDS), MFMA, G store ----
        s16x8 af[5];
        if ((lane & 15) < MROW) {
            const int abase = (lane & 15) * PADR + (lane >> 4) * 8;
#pragma unroll
            for (int kt = 0; kt < 5; ++kt)
                af[kt] = *(const s16x8*)&Ast[kt * TSTR + abase];
        } else {
#pragma unroll
            for (int kt = 0; kt < 5; ++kt)
                af[kt] = (s16x8){0, 0, 0, 0, 0, 0, 0, 0};
        }
        f32x4 acc[4];
#pragma unroll
        for (int i2 = 0; i2 < 4; ++i2) {
            acc[i2] = (f32x4){0.f, 0.f, 0.f, 0.f};
#pragma unroll
            for (int kt = 0; kt < 5; ++kt)
                acc[i2] = __builtin_amdgcn_mfma_f32_16x16x32_bf16(
                    af[kt], Bfr[i2][kt], acc[i2], 0, 0, 0);
        }
        if (lane < 16) {  // C: col=lane, row(m)=reg idx -> [n][m] b128 store
#pragma unroll
            for (int i2 = 0; i2 < 4; ++i2) {
                const int nt = w + 4 * i2;
                if (nt < 13) *(f32x4*)&G[(nt * 16 + lane) * 4] = acc[i2];
            }
        }
        __syncthreads();   // (1) G ready; Ast A-reads done

        // ---- coalesced dump of previous 64-step output chunk ----
        if ((ts & 63) == 0 && ts > 0)
            out[(size_t)(r0 + (t >> 6)) * SEQT + (ts - 64) + (t & 63)] =
                Obuf[(t >> 6) * 64 + (t & 63)];

        // ---- epilogue: LSTM1 cell update (t<204), x prefetch (204..207) ----
        if (t < 204) {
            const int m = t & 3, u = t >> 2;
            const float gi = G[u * 4 + m];
            const float gf = G[(51 + u) * 4 + m];
            const float gg = G[(102 + u) * 4 + m];
            const float go = G[(153 + u) * 4 + m];
            c1 = sigf(gf) * c1 + sigf(gi) * tanhfast(gg);
            const float h1 = sigf(go) * tanhfast(c1);
            const short hh = f2bf(h1), hl = f2bf(h1 - bf2f(hh));
            const int c0 = 2 * u;
            *(unsigned*)&Ast[(c0 >> 5) * TSTR + m * PADR + (c0 & 31)] =
                (unsigned)(unsigned short)hh |
                ((unsigned)(unsigned short)hl << 16);
            const int c2 = 102 + u;
            Ast[(c2 >> 5) * TSTR + m * PADR + (c2 & 31)] = hh;
            C1s[m * 52 + u] = c1;
        } else if (t < 208) {
            const int m = t - 204;
            const short xh = f2bf(xreg), xl = f2bf(xreg - bf2f(xh));
            Ast[4 * TSTR + m * PADR + 25] = xh;
            Ast[4 * TSTR + m * PADR + 26] = xl;
            Ast[4 * TSTR + m * PADR + 27] = xh;
            xreg = (ts + 2 < SEQT)
                       ? input[(size_t)(r0 + m) * SEQT + ts + 2] : 0.f;
        }
        __syncthreads();   // (2) h(ts), C1s ready

        // ---- z + LSTM3 (wave 0 only, runs in other waves' shadow) ----
        if (t < 64) {
            const int m = t >> 4, q = t & 3;
            float p = 0.f;
#pragma unroll
            for (int ii = 0; ii < 13; ++ii)
                p = fmaf(C1s[m * 52 + q * 13 + ii], w3[ii], p);
            p += __shfl_xor(p, 1);
            p += __shfl_xor(p, 2);
            const int base = t & ~15;
            const float pi = __shfl(p, base + 0);
            const float pf = __shfl(p, base + 4);
            const float pg = __shfl(p, base + 8);
            const float po = __shfl(p, base + 12);
            const float gi_ = pi + fmaf(whh3_0, h3, b3_0);
            const float gf_ = pf + fmaf(whh3_1, h3, b3_1);
            const float gg_ = pg + fmaf(whh3_2, h3, b3_2);
            const float go_ = po + fmaf(whh3_3, h3, b3_3);
            c3 = sigf(gf_) * c3 + sigf(gi_) * tanhfast(gg_);
            h3 = sigf(go_) * tanhfast(c3);
            if ((t & 15) == 0) Obuf[m * 64 + (ts & 63)] = c3;
        }
    }
    __syncthreads();
    // tail: ts 1984..1999 (16 per row)
    if (t < 64)
        out[(size_t)(r0 + (t >> 4)) * SEQT + (SEQT & ~63) + (t & 15)] =
            Obuf[(t >> 4) * 64 + (t & 15)];
}

extern "C" void kernel_launch(void* const* d_in, const int* in_sizes, int n_in,
                              void* d_out, int out_size, void* d_ws, size_t ws_size,
                              hipStream_t stream) {
    const float* input = (const float*)d_in[0];
    const float* W_ih1 = (const float*)d_in[1];
    const float* W_hh1 = (const float*)d_in[2];
    const float* b_ih1 = (const float*)d_in[3];
    const float* b_hh1 = (const float*)d_in[4];
    const float* W_ih3 = (const float*)d_in[5];
    const float* W_hh3 = (const float*)d_in[6];
    const float* b_ih3 = (const float*)d_in[7];
    const float* b_hh3 = (const float*)d_in[8];
    float* out = (float*)d_out;

    lstm_fused_kernel<<<NBLK, 256, 0, stream>>>(
        input, W_ih1, W_hh1, b_ih1, b_hh1, W_ih3, W_hh3, b_ih3, b_hh3, out);
}